// Round 7
// baseline (623.848 us; speedup 1.0000x reference)
//
#include <hip/hip_runtime.h>

// R7 — INSTRUMENTATION ROUND. The 2GiB harness fills (313-326us) have hidden
// our dispatches from the top-5 for six rounds. Fix: make the dispatches we
// want to see LONGER than the fills via 4 internal output sweeps.
//   probe_same4x: store-only, exact R1 mapping, 4 sweeps (~2.1GiB writes).
//   relpos4x:     full R1 compute, 4 sweeps (every sweep writes correct data).
// relpos4x runs LAST -> d_out correct. Read both dispatches' hbm_gbps /
// VALUBusy / Occupancy / LDS_conflicts next round.

typedef float f4 __attribute__((ext_vector_type(4)));

constexpr int ROWS = 136;
constexpr int THREADS = 512;
constexpr int GRID = 1024;

// ---- probe: exact R1 store mapping, store-only, 4 sweeps ----
__global__ __launch_bounds__(512)
void probe_same4x(f4* __restrict__ out)
{
    const int t = blockIdx.x * 512 + threadIdx.x;
    const f4 v = {1.0f, 1.0f, 1.0f, 1.0f};
    for (int s = 0; s < 4; ++s) {
        size_t o = (size_t)t;
        #pragma unroll 8
        for (int it = 0; it < 64; ++it) {
            out[o] = v;
            o += (size_t)524288;          // 8 MiB stride, 64 sweeps = 512 MiB
        }
    }
}

// ---- full R1 kernel, 4 sweeps (rotated start defeats loop-invariant hoist) ----
__global__ __launch_bounds__(THREADS)
void relpos4x(const int* __restrict__ asym,
              const int* __restrict__ resid,
              const int* __restrict__ ent,
              const int* __restrict__ tok,
              const int* __restrict__ sym,
              const float* __restrict__ W,
              f4* __restrict__ outv)
{
    __shared__ f4 sW[ROWS * 32];   // 69,632 B
    const int tid = threadIdx.x;

    const f4* Wv = reinterpret_cast<const f4*>(W);
    for (int k = tid; k < ROWS * 32; k += THREADS)
        sW[k] = Wv[k];
    __syncthreads();

    const int t  = blockIdx.x * THREADS + tid;
    const int c4 = t & 31;
    const int p0 = t >> 5;
    const int j  = p0 & 1023;
    const int i0 = p0 >> 10;

    const int aj = asym[j];
    const int rj = resid[j];
    const int ej = ent[j];
    const int tj = tok[j];
    const int sj = sym[j];

    const f4 vE = sW[130 * 32 + c4];

    for (int s = 0; s < 4; ++s) {
        // rotate iteration start by 16*s (mod 64): identical set of writes per
        // sweep, but compute depends on s so the compiler can't hoist sweeps.
        int itb = 16 * s;
        #pragma unroll 4
        for (int itc = 0; itc < 64; ++itc) {
            const int it = (itb + itc) & 63;
            const int i  = i0 + 16 * it;

            const int ai = asym[i];
            const int ri = resid[i];
            const int ei = ent[i];
            const int ti = tok[i];
            const int si = sym[i];

            const bool sc = (ai == aj);
            const bool sr = (ri == rj);

            int dres = min(max(rj - ri + 32, 0), 64);
            int dtok = min(max(tj - ti + 32, 0), 64);
            int dch  = min(max(sj - si + 2, 0), 4);
            if (sc)        { dres = 64; dch = 4; }
            if (sc || sr)  { dtok = 64; }
            const float se = (ei == ej) ? 1.0f : 0.0f;

            const f4 v0 = sW[dres * 32 + c4];
            const f4 v1 = sW[(65 + dtok) * 32 + c4];
            const f4 v3 = sW[(131 + dch) * 32 + c4];

            f4 r;
            r.x = fmaf(se, vE.x, v0.x + v1.x) + v3.x;
            r.y = fmaf(se, vE.y, v0.y + v1.y) + v3.y;
            r.z = fmaf(se, vE.z, v0.z + v1.z) + v3.z;
            r.w = fmaf(se, vE.w, v0.w + v1.w) + v3.w;

            outv[(size_t)t + (size_t)it * 524288] = r;
        }
    }
}

extern "C" void kernel_launch(void* const* d_in, const int* in_sizes, int n_in,
                              void* d_out, int out_size, void* d_ws, size_t ws_size,
                              hipStream_t stream) {
    const int*   asym  = (const int*)  d_in[0];
    const int*   resid = (const int*)  d_in[1];
    const int*   ent   = (const int*)  d_in[2];
    const int*   tok   = (const int*)  d_in[3];
    const int*   sym   = (const int*)  d_in[4];
    const float* W     = (const float*)d_in[5];
    f4* outv = (f4*)d_out;

    probe_same4x<<<GRID, THREADS, 0, stream>>>(outv);
    relpos4x<<<GRID, THREADS, 0, stream>>>(asym, resid, ent, tok, sym, W, outv);
}